// Round 1
// baseline (696.906 us; speedup 1.0000x reference)
//
#include <hip/hip_runtime.h>
#include <hip/hip_bf16.h>
#include <math.h>
#include <stdint.h>

#define BT   4096      // B*T
#define QD   2048      // 2*H*DH
#define DIMK 512       // DIM
#define NH   8
#define DHD  128
#define NKEY 256
#define TK   16

// ---------------------------------------------------------------------------
// Kernel 1: q = x @ Wq^T  (M=4096, N=2048, K=512), fused LayerNorm over each
// 128-col chunk (tile cols == exactly one (p,h) chunk).
// 128x128 tile, BK=8, 256 threads, 8x8 micro-tile per thread.
// ---------------------------------------------------------------------------
__global__ __launch_bounds__(256) void qproj_ln(
    const float* __restrict__ x, const float* __restrict__ Wq,
    const float* __restrict__ lng, const float* __restrict__ lnb,
    float* __restrict__ q) {
  __shared__ float As[8][128];
  __shared__ float Bs[8][128];
  const int br = blockIdx.x;          // m-tile (32)
  const int bc = blockIdx.y;          // n-tile (16) == LN chunk index
  const int tid = threadIdx.x;
  const int ty = tid >> 4, tx = tid & 15;
  const int lr = tid >> 1, lc = (tid & 1) * 4;

  const float* xA = x  + (size_t)(br * 128 + lr) * DIMK + lc;
  const float* wB = Wq + (size_t)(bc * 128 + lr) * DIMK + lc;

  float acc[8][8];
  #pragma unroll
  for (int i = 0; i < 8; i++)
    #pragma unroll
    for (int j = 0; j < 8; j++) acc[i][j] = 0.f;

  for (int kt = 0; kt < DIMK; kt += 8) {
    float4 a4 = *(const float4*)(xA + kt);
    float4 b4 = *(const float4*)(wB + kt);
    __syncthreads();
    As[lc + 0][lr] = a4.x; As[lc + 1][lr] = a4.y;
    As[lc + 2][lr] = a4.z; As[lc + 3][lr] = a4.w;
    Bs[lc + 0][lr] = b4.x; Bs[lc + 1][lr] = b4.y;
    Bs[lc + 2][lr] = b4.z; Bs[lc + 3][lr] = b4.w;
    __syncthreads();
    #pragma unroll
    for (int kk = 0; kk < 8; kk++) {
      float a[8], b[8];
      #pragma unroll
      for (int i = 0; i < 8; i++) a[i] = As[kk][ty * 8 + i];
      #pragma unroll
      for (int j = 0; j < 8; j++) b[j] = Bs[kk][tx * 8 + j];
      #pragma unroll
      for (int i = 0; i < 8; i++)
        #pragma unroll
        for (int j = 0; j < 8; j++)
          acc[i][j] = fmaf(a[i], b[j], acc[i][j]);
    }
  }

  // LayerNorm epilogue: row m's 128 values live in the 16 threads sharing ty.
  float g[8], bb[8];
  #pragma unroll
  for (int j = 0; j < 8; j++) { g[j] = lng[tx * 8 + j]; bb[j] = lnb[tx * 8 + j]; }

  #pragma unroll
  for (int i = 0; i < 8; i++) {
    float s = 0.f;
    #pragma unroll
    for (int j = 0; j < 8; j++) s += acc[i][j];
    #pragma unroll
    for (int m = 1; m < 16; m <<= 1) s += __shfl_xor(s, m);
    const float mu = s * (1.f / 128.f);
    float s2 = 0.f;
    #pragma unroll
    for (int j = 0; j < 8; j++) { float d = acc[i][j] - mu; s2 = fmaf(d, d, s2); }
    #pragma unroll
    for (int m = 1; m < 16; m <<= 1) s2 += __shfl_xor(s2, m);
    const float rstd = rsqrtf(s2 * (1.f / 128.f) + 1e-5f);
    float o[8];
    #pragma unroll
    for (int j = 0; j < 8; j++)
      o[j] = (acc[i][j] - mu) * rstd * g[j] + bb[j];
    float* qp = q + (size_t)(br * 128 + ty * 8 + i) * QD + bc * 128 + tx * 8;
    *(float4*)(qp)     = make_float4(o[0], o[1], o[2], o[3]);
    *(float4*)(qp + 4) = make_float4(o[4], o[5], o[6], o[7]);
  }
}

// ---------------------------------------------------------------------------
// Kernel 2: dots[hp] = qn(,p,h,:) @ keys[h,:,p,:]^T  (M=4096, N=256, K=128)
// per (h,p).  Same tile skeleton.  S layout: [hp][m][n].
// ---------------------------------------------------------------------------
__global__ __launch_bounds__(256) void dots_gemm(
    const float* __restrict__ q, const float* __restrict__ keys,
    float* __restrict__ S) {
  __shared__ float As[8][128];
  __shared__ float Bs[8][128];
  const int br = blockIdx.x;          // m-tile (32)
  const int bc = blockIdx.y;          // n-tile (2)
  const int hp = blockIdx.z;          // 16
  const int h = hp >> 1, p = hp & 1;
  const int tid = threadIdx.x;
  const int ty = tid >> 4, tx = tid & 15;
  const int lr = tid >> 1, lc = (tid & 1) * 4;

  const float* qA = q + (size_t)(br * 128 + lr) * QD + p * 1024 + h * 128 + lc;
  const float* kB = keys + ((size_t)((h * 256 + bc * 128 + lr) * 2 + p)) * 128 + lc;

  float acc[8][8];
  #pragma unroll
  for (int i = 0; i < 8; i++)
    #pragma unroll
    for (int j = 0; j < 8; j++) acc[i][j] = 0.f;

  for (int kt = 0; kt < DHD; kt += 8) {
    float4 a4 = *(const float4*)(qA + kt);
    float4 b4 = *(const float4*)(kB + kt);
    __syncthreads();
    As[lc + 0][lr] = a4.x; As[lc + 1][lr] = a4.y;
    As[lc + 2][lr] = a4.z; As[lc + 3][lr] = a4.w;
    Bs[lc + 0][lr] = b4.x; Bs[lc + 1][lr] = b4.y;
    Bs[lc + 2][lr] = b4.z; Bs[lc + 3][lr] = b4.w;
    __syncthreads();
    #pragma unroll
    for (int kk = 0; kk < 8; kk++) {
      float a[8], b[8];
      #pragma unroll
      for (int i = 0; i < 8; i++) a[i] = As[kk][ty * 8 + i];
      #pragma unroll
      for (int j = 0; j < 8; j++) b[j] = Bs[kk][tx * 8 + j];
      #pragma unroll
      for (int i = 0; i < 8; i++)
        #pragma unroll
        for (int j = 0; j < 8; j++)
          acc[i][j] = fmaf(a[i], b[j], acc[i][j]);
    }
  }

  float* Sp = S + (size_t)hp * BT * NKEY;
  #pragma unroll
  for (int i = 0; i < 8; i++) {
    float* pp = Sp + (size_t)(br * 128 + ty * 8 + i) * NKEY + bc * 128 + tx * 8;
    *(float4*)(pp)     = make_float4(acc[i][0], acc[i][1], acc[i][2], acc[i][3]);
    *(float4*)(pp + 4) = make_float4(acc[i][4], acc[i][5], acc[i][6], acc[i][7]);
  }
}

// ---------------------------------------------------------------------------
// Kernel 3: per (bt,h): top-16 of 256 (p=0), top-16 (p=1), 16x16 sum-combine,
// top-16 of 256 combos (tie-break = lowest flat pos, matching stable top_k),
// softmax, emit 16 weights + 16 value indices.  One wave per block.
// ---------------------------------------------------------------------------
__device__ __forceinline__ void argmax64(float& v, int& i) {
  #pragma unroll
  for (int m = 1; m < 64; m <<= 1) {
    float vo = __shfl_xor(v, m);
    int   io = __shfl_xor(i, m);
    if (vo > v || (vo == v && io < i)) { v = vo; i = io; }
  }
}

__global__ __launch_bounds__(64) void topk_combine(
    const float* __restrict__ S, float* __restrict__ W, int* __restrict__ I) {
  const int bt = blockIdx.x;
  const int h  = blockIdx.y;
  const int l  = threadIdx.x;

  const float* S0 = S + ((size_t)(h * 2 + 0) * BT + bt) * NKEY;
  const float* S1 = S + ((size_t)(h * 2 + 1) * BT + bt) * NKEY;
  float4 v0 = *(const float4*)(S0 + l * 4);
  float4 v1 = *(const float4*)(S1 + l * 4);
  float s0[4] = {v0.x, v0.y, v0.z, v0.w};
  float s1[4] = {v1.x, v1.y, v1.z, v1.w};

  float sx = 0.f, sy = 0.f; int ix = 0, iy = 0;   // lane k (<16) holds k-th

  #pragma unroll
  for (int k = 0; k < TK; k++) {                  // p = 0
    float v = s0[0]; int idx = l * 4;
    #pragma unroll
    for (int r = 1; r < 4; r++)
      if (s0[r] > v) { v = s0[r]; idx = l * 4 + r; }
    argmax64(v, idx);
    if (l == k) { sx = v; ix = idx; }
    #pragma unroll
    for (int r = 0; r < 4; r++)
      if (idx == l * 4 + r) s0[r] = -INFINITY;
  }
  #pragma unroll
  for (int k = 0; k < TK; k++) {                  // p = 1
    float v = s1[0]; int idx = l * 4;
    #pragma unroll
    for (int r = 1; r < 4; r++)
      if (s1[r] > v) { v = s1[r]; idx = l * 4 + r; }
    argmax64(v, idx);
    if (l == k) { sy = v; iy = idx; }
    #pragma unroll
    for (int r = 0; r < 4; r++)
      if (idx == l * 4 + r) s1[r] = -INFINITY;
  }

  // combined scores: flat pos = i*16+j ; lane l owns pos l*4 .. l*4+3
  float cv[4];
  #pragma unroll
  for (int r = 0; r < 4; r++) {
    const int pos = l * 4 + r;
    cv[r] = __shfl(sx, pos >> 4) + __shfl(sy, pos & 15);
  }

  float fs = 0.f; int fp = 0;
  #pragma unroll
  for (int k = 0; k < TK; k++) {
    float v = cv[0]; int pos = l * 4;
    #pragma unroll
    for (int r = 1; r < 4; r++)
      if (cv[r] > v) { v = cv[r]; pos = l * 4 + r; }
    argmax64(v, pos);
    if (l == k) { fs = v; fp = pos; }
    #pragma unroll
    for (int r = 0; r < 4; r++)
      if (pos == l * 4 + r) cv[r] = -INFINITY;
  }

  const int vi = __shfl(ix, fp >> 4) * NKEY + __shfl(iy, fp & 15);

  // softmax over the 16 selected (descending; lane 0 holds the max)
  const float mx = __shfl(fs, 0);
  float e = (l < TK) ? expf(fs - mx) : 0.f;
  float sum = e;
  #pragma unroll
  for (int m = 1; m < 64; m <<= 1) sum += __shfl_xor(sum, m);

  if (l < TK) {
    const size_t o = ((size_t)bt * NH + h) * TK + l;
    W[o] = e / sum;
    I[o] = vi;
  }
}

// ---------------------------------------------------------------------------
// Kernel 4: out[bt,:] = sum_{r<128} w[bt,r] * values[idx[bt,r], :]
// 128 threads, one float4 of the 512-dim output per thread.
// ---------------------------------------------------------------------------
__global__ __launch_bounds__(128) void gather_out(
    const float* __restrict__ values, const float* __restrict__ W,
    const int* __restrict__ I, float* __restrict__ out) {
  const int bt = blockIdx.x;
  const int t  = threadIdx.x;
  __shared__ float wsm[128];
  __shared__ int   ism[128];
  wsm[t] = W[(size_t)bt * 128 + t];
  ism[t] = I[(size_t)bt * 128 + t];
  __syncthreads();
  float4 acc = make_float4(0.f, 0.f, 0.f, 0.f);
  #pragma unroll 4
  for (int r = 0; r < 128; r++) {
    const float w = wsm[r];
    const float4 v = *(const float4*)(values + (size_t)ism[r] * DIMK + t * 4);
    acc.x = fmaf(w, v.x, acc.x);
    acc.y = fmaf(w, v.y, acc.y);
    acc.z = fmaf(w, v.z, acc.z);
    acc.w = fmaf(w, v.w, acc.w);
  }
  *(float4*)(out + (size_t)bt * DIMK + t * 4) = acc;
}

// ---------------------------------------------------------------------------
extern "C" void kernel_launch(void* const* d_in, const int* in_sizes, int n_in,
                              void* d_out, int out_size, void* d_ws, size_t ws_size,
                              hipStream_t stream) {
  const float* x      = (const float*)d_in[0];
  const float* Wq     = (const float*)d_in[1];
  const float* lng    = (const float*)d_in[2];
  const float* lnb    = (const float*)d_in[3];
  const float* keys   = (const float*)d_in[4];
  const float* values = (const float*)d_in[5];
  float* out = (float*)d_out;

  char* ws = (char*)d_ws;
  float* q = (float*)(ws);                                  // 32 MB
  float* S = (float*)(ws + (size_t)32 * 1024 * 1024);       // 64 MB
  float* W = (float*)(ws + (size_t)96 * 1024 * 1024);       //  2 MB
  int*   I = (int*)  (ws + (size_t)98 * 1024 * 1024);       //  2 MB

  qproj_ln    <<<dim3(32, 16),    256, 0, stream>>>(x, Wq, lng, lnb, q);
  dots_gemm   <<<dim3(32, 2, 16), 256, 0, stream>>>(q, keys, S);
  topk_combine<<<dim3(4096, 8),   64,  0, stream>>>(S, W, I);
  gather_out  <<<dim3(4096),      128, 0, stream>>>(values, W, I, out);
}

// Round 3
// 549.565 us; speedup vs baseline: 1.2681x; 1.2681x over previous
//
#include <hip/hip_runtime.h>
#include <hip/hip_bf16.h>
#include <math.h>
#include <stdint.h>

#define BT   4096      // B*T
#define QD   2048      // 2*H*DH
#define DIMK 512       // DIM
#define NH   8
#define DHD  128
#define NKEY 256
#define TK   16

// ---------------------------------------------------------------------------
// Kernel 1: q = x @ Wq^T  (M=4096, N=2048, K=512), fused LayerNorm over each
// 128-col chunk (tile cols == exactly one (p,h) chunk).
// 128x128 tile, BK=8, 256 threads, 8x8 micro-tile per thread.
// ---------------------------------------------------------------------------
__global__ __launch_bounds__(256) void qproj_ln(
    const float* __restrict__ x, const float* __restrict__ Wq,
    const float* __restrict__ lng, const float* __restrict__ lnb,
    float* __restrict__ q) {
  __shared__ float As[8][128];
  __shared__ float Bs[8][128];
  const int br = blockIdx.x;          // m-tile (32)
  const int bc = blockIdx.y;          // n-tile (16) == LN chunk index
  const int tid = threadIdx.x;
  const int ty = tid >> 4, tx = tid & 15;
  const int lr = tid >> 1, lc = (tid & 1) * 4;

  const float* xA = x  + (size_t)(br * 128 + lr) * DIMK + lc;
  const float* wB = Wq + (size_t)(bc * 128 + lr) * DIMK + lc;

  float acc[8][8];
  #pragma unroll
  for (int i = 0; i < 8; i++)
    #pragma unroll
    for (int j = 0; j < 8; j++) acc[i][j] = 0.f;

  for (int kt = 0; kt < DIMK; kt += 8) {
    float4 a4 = *(const float4*)(xA + kt);
    float4 b4 = *(const float4*)(wB + kt);
    __syncthreads();
    As[lc + 0][lr] = a4.x; As[lc + 1][lr] = a4.y;
    As[lc + 2][lr] = a4.z; As[lc + 3][lr] = a4.w;
    Bs[lc + 0][lr] = b4.x; Bs[lc + 1][lr] = b4.y;
    Bs[lc + 2][lr] = b4.z; Bs[lc + 3][lr] = b4.w;
    __syncthreads();
    #pragma unroll
    for (int kk = 0; kk < 8; kk++) {
      float a[8], b[8];
      #pragma unroll
      for (int i = 0; i < 8; i++) a[i] = As[kk][ty * 8 + i];
      #pragma unroll
      for (int j = 0; j < 8; j++) b[j] = Bs[kk][tx * 8 + j];
      #pragma unroll
      for (int i = 0; i < 8; i++)
        #pragma unroll
        for (int j = 0; j < 8; j++)
          acc[i][j] = fmaf(a[i], b[j], acc[i][j]);
    }
  }

  // LayerNorm epilogue: row m's 128 values live in the 16 threads sharing ty.
  float g[8], bb[8];
  #pragma unroll
  for (int j = 0; j < 8; j++) { g[j] = lng[tx * 8 + j]; bb[j] = lnb[tx * 8 + j]; }

  #pragma unroll
  for (int i = 0; i < 8; i++) {
    float s = 0.f;
    #pragma unroll
    for (int j = 0; j < 8; j++) s += acc[i][j];
    #pragma unroll
    for (int m = 1; m < 16; m <<= 1) s += __shfl_xor(s, m);
    const float mu = s * (1.f / 128.f);
    float s2 = 0.f;
    #pragma unroll
    for (int j = 0; j < 8; j++) { float d = acc[i][j] - mu; s2 = fmaf(d, d, s2); }
    #pragma unroll
    for (int m = 1; m < 16; m <<= 1) s2 += __shfl_xor(s2, m);
    const float rstd = rsqrtf(s2 * (1.f / 128.f) + 1e-5f);
    float o[8];
    #pragma unroll
    for (int j = 0; j < 8; j++)
      o[j] = (acc[i][j] - mu) * rstd * g[j] + bb[j];
    float* qp = q + (size_t)(br * 128 + ty * 8 + i) * QD + bc * 128 + tx * 8;
    *(float4*)(qp)     = make_float4(o[0], o[1], o[2], o[3]);
    *(float4*)(qp + 4) = make_float4(o[4], o[5], o[6], o[7]);
  }
}

// ---------------------------------------------------------------------------
// Kernel 2: dots[hp] = qn(,p,h,:) @ keys[h,:,p,:]^T  (M=4096, N=256, K=128)
// per (h,p).  Same tile skeleton.  S layout: [hp][m][n].
// ---------------------------------------------------------------------------
__global__ __launch_bounds__(256) void dots_gemm(
    const float* __restrict__ q, const float* __restrict__ keys,
    float* __restrict__ S) {
  __shared__ float As[8][128];
  __shared__ float Bs[8][128];
  const int br = blockIdx.x;          // m-tile (32)
  const int bc = blockIdx.y;          // n-tile (2)
  const int hp = blockIdx.z;          // 16
  const int h = hp >> 1, p = hp & 1;
  const int tid = threadIdx.x;
  const int ty = tid >> 4, tx = tid & 15;
  const int lr = tid >> 1, lc = (tid & 1) * 4;

  const float* qA = q + (size_t)(br * 128 + lr) * QD + p * 1024 + h * 128 + lc;
  const float* kB = keys + ((size_t)((h * 256 + bc * 128 + lr) * 2 + p)) * 128 + lc;

  float acc[8][8];
  #pragma unroll
  for (int i = 0; i < 8; i++)
    #pragma unroll
    for (int j = 0; j < 8; j++) acc[i][j] = 0.f;

  for (int kt = 0; kt < DHD; kt += 8) {
    float4 a4 = *(const float4*)(qA + kt);
    float4 b4 = *(const float4*)(kB + kt);
    __syncthreads();
    As[lc + 0][lr] = a4.x; As[lc + 1][lr] = a4.y;
    As[lc + 2][lr] = a4.z; As[lc + 3][lr] = a4.w;
    Bs[lc + 0][lr] = b4.x; Bs[lc + 1][lr] = b4.y;
    Bs[lc + 2][lr] = b4.z; Bs[lc + 3][lr] = b4.w;
    __syncthreads();
    #pragma unroll
    for (int kk = 0; kk < 8; kk++) {
      float a[8], b[8];
      #pragma unroll
      for (int i = 0; i < 8; i++) a[i] = As[kk][ty * 8 + i];
      #pragma unroll
      for (int j = 0; j < 8; j++) b[j] = Bs[kk][tx * 8 + j];
      #pragma unroll
      for (int i = 0; i < 8; i++)
        #pragma unroll
        for (int j = 0; j < 8; j++)
          acc[i][j] = fmaf(a[i], b[j], acc[i][j]);
    }
  }

  float* Sp = S + (size_t)hp * BT * NKEY;
  #pragma unroll
  for (int i = 0; i < 8; i++) {
    float* pp = Sp + (size_t)(br * 128 + ty * 8 + i) * NKEY + bc * 128 + tx * 8;
    *(float4*)(pp)     = make_float4(acc[i][0], acc[i][1], acc[i][2], acc[i][3]);
    *(float4*)(pp + 4) = make_float4(acc[i][4], acc[i][5], acc[i][6], acc[i][7]);
  }
}

// ---------------------------------------------------------------------------
// Kernel 3 (REWRITTEN): exact top-16 selection via 32-round radix-select
// (MSB bit-descent on monotone float->u32 keys) — no cross-lane shuffles.
// Output is order-free: downstream (softmax + weighted sum) is permutation-
// invariant, so we only need the exact top-16 SET per selection.
// Ties broken by lowest flat index via mbcnt ranks (matches stable top_k).
// One wave per (bt,h); lane l owns flat indices l*4..l*4+3.
// ---------------------------------------------------------------------------
__device__ __forceinline__ uint32_t f2u(float f) {
  uint32_t b = __float_as_uint(f);
  return b ^ ((uint32_t)((int32_t)b >> 31) | 0x80000000u);
}
__device__ __forceinline__ float u2f(uint32_t u) {
  uint32_t b = (u & 0x80000000u) ? (u ^ 0x80000000u) : ~u;
  return __uint_as_float(b);
}
__device__ __forceinline__ int cnt_lt(uint64_t m) {   // popcount(m & lanes_below)
  return __builtin_amdgcn_mbcnt_hi((uint32_t)(m >> 32),
         __builtin_amdgcn_mbcnt_lo((uint32_t)m, 0));
}

__global__ __launch_bounds__(64) void topk_combine(
    const float* __restrict__ S, float* __restrict__ W, int* __restrict__ I) {
  const int bt = blockIdx.x;
  const int h  = blockIdx.y;
  const int l  = threadIdx.x;

  __shared__ __align__(16) float sx_lds[16], sy_lds[16], w_lds[16];
  __shared__ __align__(16) int   ix_lds[16], iy_lds[16], vi_lds[16];

  const float* S0 = S + ((size_t)(h * 2 + 0) * BT + bt) * NKEY;
  const float* S1 = S + ((size_t)(h * 2 + 1) * BT + bt) * NKEY;
  float4 v0 = *(const float4*)(S0 + l * 4);
  float4 v1 = *(const float4*)(S1 + l * 4);
  float s0[4] = {v0.x, v0.y, v0.z, v0.w};
  float s1[4] = {v1.x, v1.y, v1.z, v1.w};
  uint32_t u0[4], u1[4];
  #pragma unroll
  for (int r = 0; r < 4; r++) { u0[r] = f2u(s0[r]); u1[r] = f2u(s1[r]); }

  // --- radix-select tau for p=0 and p=1, interleaved for ILP ---
  uint32_t pfx0 = 0u, pfx1 = 0u;
  #pragma unroll
  for (int b = 31; b >= 0; b--) {
    const uint32_t t0 = pfx0 | (1u << b);
    const uint32_t t1 = pfx1 | (1u << b);
    int c0 = 0, c1 = 0;
    #pragma unroll
    for (int r = 0; r < 4; r++) {
      c0 += __popcll(__ballot(u0[r] >= t0));
      c1 += __popcll(__ballot(u1[r] >= t1));
    }
    if (c0 >= TK) pfx0 = t0;
    if (c1 >= TK) pfx1 = t1;
  }

  // --- select exactly 16 per p (ties: lowest flat index), write to LDS ---
  {
    uint64_t mgt[4], meq[4];
    int ngt = 0, below_gt = 0, below_eq = 0;
    #pragma unroll
    for (int r = 0; r < 4; r++) {
      mgt[r] = __ballot(u0[r] > pfx0);
      meq[r] = __ballot(u0[r] == pfx0);
      ngt += __popcll(mgt[r]);
      below_gt += cnt_lt(mgt[r]);
      below_eq += cnt_lt(meq[r]);
    }
    const int need = TK - ngt;
    int loc_gt = 0, loc_eq = 0;
    #pragma unroll
    for (int r = 0; r < 4; r++) {
      const bool isgt = (u0[r] > pfx0), iseq = (u0[r] == pfx0);
      int slot = -1;
      if (isgt) slot = below_gt + loc_gt;
      else if (iseq) { const int re = below_eq + loc_eq; if (re < need) slot = ngt + re; }
      if (slot >= 0) { sx_lds[slot] = s0[r]; ix_lds[slot] = l * 4 + r; }
      loc_gt += isgt; loc_eq += iseq;
    }
  }
  {
    uint64_t mgt[4], meq[4];
    int ngt = 0, below_gt = 0, below_eq = 0;
    #pragma unroll
    for (int r = 0; r < 4; r++) {
      mgt[r] = __ballot(u1[r] > pfx1);
      meq[r] = __ballot(u1[r] == pfx1);
      ngt += __popcll(mgt[r]);
      below_gt += cnt_lt(mgt[r]);
      below_eq += cnt_lt(meq[r]);
    }
    const int need = TK - ngt;
    int loc_gt = 0, loc_eq = 0;
    #pragma unroll
    for (int r = 0; r < 4; r++) {
      const bool isgt = (u1[r] > pfx1), iseq = (u1[r] == pfx1);
      int slot = -1;
      if (isgt) slot = below_gt + loc_gt;
      else if (iseq) { const int re = below_eq + loc_eq; if (re < need) slot = ngt + re; }
      if (slot >= 0) { sy_lds[slot] = s1[r]; iy_lds[slot] = l * 4 + r; }
      loc_gt += isgt; loc_eq += iseq;
    }
  }
  __syncthreads();

  // --- combined 16x16 sums: pos = l*4+r, i = l>>2 (lane-uniform), j = (l&3)*4+r
  const float sxv = sx_lds[l >> 2];
  const float4 syv = *(const float4*)&sy_lds[(l & 3) * 4];
  float cv[4] = {sxv + syv.x, sxv + syv.y, sxv + syv.z, sxv + syv.w};
  uint32_t uc[4];
  #pragma unroll
  for (int r = 0; r < 4; r++) uc[r] = f2u(cv[r]);

  uint32_t pfx2 = 0u;
  #pragma unroll
  for (int b = 31; b >= 0; b--) {
    const uint32_t t2 = pfx2 | (1u << b);
    int c2 = 0;
    #pragma unroll
    for (int r = 0; r < 4; r++) c2 += __popcll(__ballot(uc[r] >= t2));
    if (c2 >= TK) pfx2 = t2;
  }

  // softmax shift by tau2 (exact 16th-largest): exps in [1, e^(max-tau2)], safe.
  const float tau2f = u2f(pfx2);
  const int ivx = ix_lds[l >> 2];
  const int4 iyv = *(const int4*)&iy_lds[(l & 3) * 4];
  const int iy4[4] = {iyv.x, iyv.y, iyv.z, iyv.w};
  {
    uint64_t mgt[4], meq[4];
    int ngt = 0, below_gt = 0, below_eq = 0;
    #pragma unroll
    for (int r = 0; r < 4; r++) {
      mgt[r] = __ballot(uc[r] > pfx2);
      meq[r] = __ballot(uc[r] == pfx2);
      ngt += __popcll(mgt[r]);
      below_gt += cnt_lt(mgt[r]);
      below_eq += cnt_lt(meq[r]);
    }
    const int need = TK - ngt;
    int loc_gt = 0, loc_eq = 0;
    #pragma unroll
    for (int r = 0; r < 4; r++) {
      const bool isgt = (uc[r] > pfx2), iseq = (uc[r] == pfx2);
      int slot = -1;
      if (isgt) slot = below_gt + loc_gt;
      else if (iseq) { const int re = below_eq + loc_eq; if (re < need) slot = ngt + re; }
      if (slot >= 0) {
        w_lds[slot]  = __expf(cv[r] - tau2f);
        vi_lds[slot] = ivx * NKEY + iy4[r];
      }
      loc_gt += isgt; loc_eq += iseq;
    }
  }
  __syncthreads();

  if (l < TK) {
    const float4 wa = *(const float4*)&w_lds[0];
    const float4 wb = *(const float4*)&w_lds[4];
    const float4 wc = *(const float4*)&w_lds[8];
    const float4 wd = *(const float4*)&w_lds[12];
    const float sum = (wa.x + wa.y + wa.z + wa.w) + (wb.x + wb.y + wb.z + wb.w)
                    + (wc.x + wc.y + wc.z + wc.w) + (wd.x + wd.y + wd.z + wd.w);
    const size_t o = ((size_t)bt * NH + h) * TK + l;
    W[o] = w_lds[l] / sum;
    I[o] = vi_lds[l];
  }
}

// ---------------------------------------------------------------------------
// Kernel 4: out[bt,:] = sum_{r<128} w[bt,r] * values[idx[bt,r], :]
// 128 threads, one float4 of the 512-dim output per thread.
// ---------------------------------------------------------------------------
__global__ __launch_bounds__(128) void gather_out(
    const float* __restrict__ values, const float* __restrict__ W,
    const int* __restrict__ I, float* __restrict__ out) {
  const int bt = blockIdx.x;
  const int t  = threadIdx.x;
  __shared__ float wsm[128];
  __shared__ int   ism[128];
  wsm[t] = W[(size_t)bt * 128 + t];
  ism[t] = I[(size_t)bt * 128 + t];
  __syncthreads();
  float4 acc = make_float4(0.f, 0.f, 0.f, 0.f);
  #pragma unroll 4
  for (int r = 0; r < 128; r++) {
    const float w = wsm[r];
    const float4 v = *(const float4*)(values + (size_t)ism[r] * DIMK + t * 4);
    acc.x = fmaf(w, v.x, acc.x);
    acc.y = fmaf(w, v.y, acc.y);
    acc.z = fmaf(w, v.z, acc.z);
    acc.w = fmaf(w, v.w, acc.w);
  }
  *(float4*)(out + (size_t)bt * DIMK + t * 4) = acc;
}

// ---------------------------------------------------------------------------
extern "C" void kernel_launch(void* const* d_in, const int* in_sizes, int n_in,
                              void* d_out, int out_size, void* d_ws, size_t ws_size,
                              hipStream_t stream) {
  const float* x      = (const float*)d_in[0];
  const float* Wq     = (const float*)d_in[1];
  const float* lng    = (const float*)d_in[2];
  const float* lnb    = (const float*)d_in[3];
  const float* keys   = (const float*)d_in[4];
  const float* values = (const float*)d_in[5];
  float* out = (float*)d_out;

  char* ws = (char*)d_ws;
  float* q = (float*)(ws);                                  // 32 MB
  float* S = (float*)(ws + (size_t)32 * 1024 * 1024);       // 64 MB
  float* W = (float*)(ws + (size_t)96 * 1024 * 1024);       //  2 MB
  int*   I = (int*)  (ws + (size_t)98 * 1024 * 1024);       //  2 MB

  qproj_ln    <<<dim3(32, 16),    256, 0, stream>>>(x, Wq, lng, lnb, q);
  dots_gemm   <<<dim3(32, 2, 16), 256, 0, stream>>>(q, keys, S);
  topk_combine<<<dim3(4096, 8),   64,  0, stream>>>(S, W, I);
  gather_out  <<<dim3(4096),      128, 0, stream>>>(values, W, I, out);
}